// Round 11
// baseline (3505.790 us; speedup 1.0000x reference)
//
#include <hip/hip_runtime.h>
#include <math.h>

#define B_ 1024
#define D_ 2048
#define H_ 2048
#define E_ 16
#define K_ 8
#define KEEP_ 6
#define EXP_ID_ 0

// ---------------- ws layout ----------------
#define WS_OUTALL 0
#define WS_IDX    134217728
#define WS_VALS   (134217728 + 32768)
#define WS_ENERGY (134217728 + 65536)

// ---------------- 1. gating: one wave per row, f64 ----------------
__global__ __launch_bounds__(64) void gate_kernel(
    const float* __restrict__ x, const float* __restrict__ Wg,
    const float* __restrict__ bg, int* __restrict__ idx, float* __restrict__ vals) {
  const int b = blockIdx.x;
  const int lane = threadIdx.x;
  double acc[E_];
#pragma unroll
  for (int e = 0; e < E_; ++e) acc[e] = 0.0;
  for (int d = lane; d < D_; d += 64) {
    double xv = (double)x[(size_t)b * D_ + d];
    const float* w = Wg + (size_t)d * E_;
#pragma unroll
    for (int e = 0; e < E_; ++e) acc[e] = fma(xv, (double)w[e], acc[e]);
  }
  for (int off = 32; off > 0; off >>= 1) {
#pragma unroll
    for (int e = 0; e < E_; ++e) acc[e] += __shfl_down(acc[e], off, 64);
  }
  if (lane == 0) {
    double logit[E_];
#pragma unroll
    for (int e = 0; e < E_; ++e) logit[e] = acc[e] + (double)bg[e];
    double m = logit[0];
#pragma unroll
    for (int e = 1; e < E_; ++e) m = fmax(m, logit[e]);
    double p[E_], s = 0.0;
#pragma unroll
    for (int e = 0; e < E_; ++e) { p[e] = exp(logit[e] - m); s += p[e]; }
#pragma unroll
    for (int e = 0; e < E_; ++e) p[e] = p[e] / s;
    unsigned taken = 0;
    for (int j = 0; j < K_; ++j) {
      int best = -1; double bv = -1.0;
#pragma unroll
      for (int e = 0; e < E_; ++e)
        if (!((taken >> e) & 1u) && p[e] > bv) { bv = p[e]; best = e; }
      taken |= (1u << best);
      idx[b * K_ + j] = best;
      vals[b * K_ + j] = (float)bv;
    }
  }
}

// ---- 2. GEMM (f64 accumulate = truth): out_all[b,e,h] ----
#define BM 64
#define BN 64
#define BK 16

__global__ __launch_bounds__(256) void gemm_expert_kernel(
    const float* __restrict__ X, const float* __restrict__ We,
    const float* __restrict__ be, float* __restrict__ out_all) {
  const int e  = blockIdx.z;
  const int m0 = blockIdx.y * BM;
  const int n0 = blockIdx.x * BN;
  const float* Bmat = We + (size_t)e * D_ * H_;

  __shared__ double As[BK][BM];
  __shared__ double Bs[BK][BN];

  const int tid = threadIdx.x;
  const int tx = tid % 16, ty = tid / 16;
  const int arow  = tid / 4;
  const int acol4 = (tid % 4) * 4;
  const int brow  = tid / 16;
  const int bcol4 = (tid % 16) * 4;

  double acc[4][4] = {};

  for (int k0 = 0; k0 < D_; k0 += BK) {
    float4 av = *(const float4*)(X + (size_t)(m0 + arow) * D_ + k0 + acol4);
    float4 bv = *(const float4*)(Bmat + (size_t)(k0 + brow) * H_ + n0 + bcol4);
    __syncthreads();
    As[acol4 + 0][arow] = (double)av.x;
    As[acol4 + 1][arow] = (double)av.y;
    As[acol4 + 2][arow] = (double)av.z;
    As[acol4 + 3][arow] = (double)av.w;
    Bs[brow][bcol4 + 0] = (double)bv.x;
    Bs[brow][bcol4 + 1] = (double)bv.y;
    Bs[brow][bcol4 + 2] = (double)bv.z;
    Bs[brow][bcol4 + 3] = (double)bv.w;
    __syncthreads();
#pragma unroll
    for (int kk = 0; kk < BK; ++kk) {
      double a0 = As[kk][ty * 4 + 0];
      double a1 = As[kk][ty * 4 + 1];
      double a2 = As[kk][ty * 4 + 2];
      double a3 = As[kk][ty * 4 + 3];
      double b0 = Bs[kk][tx * 4 + 0];
      double b1 = Bs[kk][tx * 4 + 1];
      double b2 = Bs[kk][tx * 4 + 2];
      double b3 = Bs[kk][tx * 4 + 3];
      acc[0][0] = fma(a0, b0, acc[0][0]);
      acc[0][1] = fma(a0, b1, acc[0][1]);
      acc[0][2] = fma(a0, b2, acc[0][2]);
      acc[0][3] = fma(a0, b3, acc[0][3]);
      acc[1][0] = fma(a1, b0, acc[1][0]);
      acc[1][1] = fma(a1, b1, acc[1][1]);
      acc[1][2] = fma(a1, b2, acc[1][2]);
      acc[1][3] = fma(a1, b3, acc[1][3]);
      acc[2][0] = fma(a2, b0, acc[2][0]);
      acc[2][1] = fma(a2, b1, acc[2][1]);
      acc[2][2] = fma(a2, b2, acc[2][2]);
      acc[2][3] = fma(a2, b3, acc[2][3]);
      acc[3][0] = fma(a3, b0, acc[3][0]);
      acc[3][1] = fma(a3, b1, acc[3][1]);
      acc[3][2] = fma(a3, b2, acc[3][2]);
      acc[3][3] = fma(a3, b3, acc[3][3]);
    }
  }
#pragma unroll
  for (int i = 0; i < 4; ++i) {
    const int m = m0 + ty * 4 + i;
    const int h = n0 + tx * 4;
    float4 o;
    o.x = (float)(acc[i][0] + (double)be[(size_t)e * H_ + h + 0]);
    o.y = (float)(acc[i][1] + (double)be[(size_t)e * H_ + h + 1]);
    o.z = (float)(acc[i][2] + (double)be[(size_t)e * H_ + h + 2]);
    o.w = (float)(acc[i][3] + (double)be[(size_t)e * H_ + h + 3]);
    *(float4*)(out_all + ((size_t)m * E_ + e) * H_ + h) = o;
  }
}

// ---- 3. energy: bit-replica of numpy f32 logsumexp ----
//   cos:  f32 IEEE ops (np bits)
//   m:    f32 max (exact)
//   exp:  correctly-rounded f32 (via f64)
//   sum:  numpy pairwise_sum EXACT structure (16 x 128-blocks, 8 chains of
//         16 sequential f32 adds, fixed combine tree, all f32)
//   E:    m + (f32)log(S)   (f32 add, as np)
__global__ __launch_bounds__(256) void energy_kernel(
    const float* __restrict__ out_all, const int* __restrict__ idx,
    float* __restrict__ energy) {
  const int b = blockIdx.x, j = blockIdx.y, t = threadIdx.x;
  const int e = idx[b * K_ + j];
  if (e == EXP_ID_) {
    // cos==1.0 everywhere: m=1, terms exp(0)=1, pairwise sum of 2048 ones is
    // exact at every step -> S=2048.0f; E = 1.0f + log32(2048)
    if (t == 0) energy[b * K_ + j] = 1.0f + (float)log(2048.0);
    return;
  }
  const float* rep = out_all + ((size_t)b * E_ + EXP_ID_) * H_;
  const float* ok  = out_all + ((size_t)b * E_ + e) * H_;

  __shared__ float cs[H_];      // 8 KB: cos values in h-order
  __shared__ float red[256];
  __shared__ float chain[128];

  float mx = -2.0f;
  for (int h = t; h < H_; h += 256) {
    float r = rep[h], o = ok[h];
    float num = r * o;                        // f32, np bits
    float den = fabsf(r) * fabsf(o) + 1e-8f;  // f32, np bits
    float c = num / den;                      // f32, np bits
    cs[h] = c;
    mx = fmaxf(mx, c);
  }
  red[t] = mx;
  __syncthreads();
  for (int off = 128; off > 0; off >>= 1) {
    if (t < off) red[t] = fmaxf(red[t], red[t + off]);
    __syncthreads();
  }
  const float m = red[0];
  __syncthreads();

  // numpy pairwise base blocks: blk = t>>3 in [0,16), jj = t&7 accumulator lane
  if (t < 128) {
    const int blk = t >> 3, jj = t & 7;
    const float* base = cs + blk * 128;
    float d0 = base[jj] - m;                       // f32 subtract, np bits
    float r = (float)exp((double)d0);              // CR f32 exp
#pragma unroll
    for (int q = 1; q < 16; ++q) {
      float dq = base[q * 8 + jj] - m;
      float term = (float)exp((double)dq);
      r = r + term;                                // sequential f32 adds
    }
    chain[t] = r;
  }
  __syncthreads();

  if (t == 0) {
    float Bsum[16];
#pragma unroll
    for (int blk = 0; blk < 16; ++blk) {
      const float* c8 = chain + blk * 8;
      float s01 = c8[0] + c8[1];
      float s23 = c8[2] + c8[3];
      float s45 = c8[4] + c8[5];
      float s67 = c8[6] + c8[7];
      Bsum[blk] = (s01 + s23) + (s45 + s67);
    }
    float C[8], D[4], Ee[2];
#pragma unroll
    for (int i = 0; i < 8; ++i) C[i] = Bsum[2 * i] + Bsum[2 * i + 1];
#pragma unroll
    for (int i = 0; i < 4; ++i) D[i] = C[2 * i] + C[2 * i + 1];
#pragma unroll
    for (int i = 0; i < 2; ++i) Ee[i] = D[2 * i] + D[2 * i + 1];
    float S = Ee[0] + Ee[1];
    energy[b * K_ + j] = m + (float)log((double)S);   // f32 add, np's final E
  }
}

// ---- 4. select: stable rank on f32 E bits (exact ties -> lower j), keep 6 ----
__global__ __launch_bounds__(256) void final_kernel(
    const float* __restrict__ out_all, const int* __restrict__ idx,
    const float* __restrict__ vals, const float* __restrict__ energy,
    float* __restrict__ out) {
  const int b = blockIdx.x;
  const int h = blockIdx.y * 256 + threadIdx.x;
  float En[K_];
#pragma unroll
  for (int j = 0; j < K_; ++j) En[j] = energy[b * K_ + j];
  double s = 0.0;
#pragma unroll
  for (int j = 0; j < K_; ++j) {
    int pos = 0;
#pragma unroll
    for (int j2 = 0; j2 < K_; ++j2)
      pos += (En[j2] < En[j]) || (En[j2] == En[j] && j2 < j);
    if (pos < KEEP_) {
      int e = idx[b * K_ + j];
      s += (double)vals[b * K_ + j] *
           (double)out_all[((size_t)b * E_ + e) * H_ + h];
    }
  }
  out[(size_t)b * H_ + h] = (float)s;
}

// ---------------- launch ----------------
extern "C" void kernel_launch(void* const* d_in, const int* in_sizes, int n_in,
                              void* d_out, int out_size, void* d_ws, size_t ws_size,
                              hipStream_t stream) {
  const float* x  = (const float*)d_in[0];
  const float* Wg = (const float*)d_in[1];
  const float* bg = (const float*)d_in[2];
  const float* We = (const float*)d_in[3];
  const float* be = (const float*)d_in[4];
  float* out = (float*)d_out;

  char* ws = (char*)d_ws;
  float* out_all = (float*)(ws + WS_OUTALL);
  int*   idx     = (int*)(ws + WS_IDX);
  float* vals    = (float*)(ws + WS_VALS);
  float* energy  = (float*)(ws + WS_ENERGY);

  gate_kernel<<<dim3(B_), dim3(64), 0, stream>>>(x, Wg, bg, idx, vals);

  gemm_expert_kernel<<<dim3(H_ / BN, B_ / BM, E_), dim3(256), 0, stream>>>(
      x, We, be, out_all);

  energy_kernel<<<dim3(B_, K_), dim3(256), 0, stream>>>(out_all, idx, energy);

  final_kernel<<<dim3(B_, H_ / 256), dim3(256), 0, stream>>>(
      out_all, idx, vals, energy, out);
}